// Round 13
// baseline (402.624 us; speedup 1.0000x reference)
//
#include <hip/hip_runtime.h>
#include <math.h>

#define H 2048
#define S 2048
#define NH 32
#define HD 64
#define DFF 8192

typedef __attribute__((ext_vector_type(4))) float f32x4;
typedef __attribute__((ext_vector_type(8))) short short8;
typedef __attribute__((ext_vector_type(4))) short s16x4;

static __device__ __forceinline__ ushort f2bf(float f) {
  unsigned u = __float_as_uint(f);
  u += 0x7fff + ((u >> 16) & 1);
  return (ushort)(u >> 16);
}

static __device__ __forceinline__ void gl_lds16(const ushort* g, ushort* l) {
  __builtin_amdgcn_global_load_lds(
      (__attribute__((address_space(1))) const void*)g,
      (__attribute__((address_space(3))) void*)l, 16, 0, 0);
}

// all six weight transposes (fp32 -> bf16, [K][N] -> [N][K]) in one flat launch
__global__ __launch_bounds__(256) void transpose_all_kernel(
    const float* __restrict__ wq, const float* __restrict__ wk,
    const float* __restrict__ wv, const float* __restrict__ wo,
    const float* __restrict__ w1, const float* __restrict__ w2,
    ushort* __restrict__ oQKV, ushort* __restrict__ oO,
    ushort* __restrict__ o1, ushort* __restrict__ o2) {
  __shared__ __align__(16) ushort tile[64][72];
  int id = blockIdx.x;
  const float* W;
  ushort* Wt;
  int K, N, bx, by;
  if (id < 4096) {
    int which = id >> 10, r = id & 1023;
    bx = r & 31; by = r >> 5; K = H; N = H;
    W = (which == 0) ? wq : (which == 1) ? wk : (which == 2) ? wv : wo;
    Wt = (which == 3) ? oO : oQKV + (size_t)which * H * H;
  } else if (id < 8192) {
    int r = id - 4096;
    bx = r & 127; by = r >> 7; K = H; N = DFF;
    W = w1; Wt = o1;
  } else {
    int r = id - 8192;
    bx = r & 31; by = r >> 5; K = DFF; N = H;
    W = w2; Wt = o2;
  }
  int n0 = bx * 64, k0 = by * 64;
  int t = threadIdx.x;
  int lk = t >> 4;
  int ln4 = (t & 15) * 4;
#pragma unroll
  for (int p = 0; p < 4; p++) {
    int k = p * 16 + lk;
    float4 v = *reinterpret_cast<const float4*>(&W[(size_t)(k0 + k) * N + n0 + ln4]);
    float vv[4] = {v.x, v.y, v.z, v.w};
#pragma unroll
    for (int i = 0; i < 4; i++) {
      int row = ln4 + i;
      int slot = ((k >> 3) ^ (row & 7));
      tile[row][(slot << 3) + (k & 7)] = f2bf(vv[i]);
    }
  }
  __syncthreads();
  int n = t >> 2;
  int kq = (t & 3) * 8;
#pragma unroll
  for (int p = 0; p < 2; p++) {
    int kk = kq + p * 32;
    int slot = ((kk >> 3) ^ (n & 7));
    short8 o = *reinterpret_cast<const short8*>(&tile[n][slot << 3]);
    *reinterpret_cast<short8*>(&Wt[(size_t)(n0 + n) * K + k0 + kk]) = o;
  }
}

// LayerNorm fp32 -> bf16
__global__ __launch_bounds__(256) void ln_kernel(
    const float* __restrict__ x, const float* __restrict__ w,
    const float* __restrict__ b, ushort* __restrict__ out) {
  int row = blockIdx.x, t = threadIdx.x;
  const float4* xr = reinterpret_cast<const float4*>(x + (size_t)row * H);
  float4 v0 = xr[t * 2], v1 = xr[t * 2 + 1];
  float s = v0.x + v0.y + v0.z + v0.w + v1.x + v1.y + v1.z + v1.w;
  float q = v0.x * v0.x + v0.y * v0.y + v0.z * v0.z + v0.w * v0.w +
            v1.x * v1.x + v1.y * v1.y + v1.z * v1.z + v1.w * v1.w;
#pragma unroll
  for (int off = 32; off > 0; off >>= 1) {
    s += __shfl_down(s, off, 64);
    q += __shfl_down(q, off, 64);
  }
  __shared__ float sm[8];
  int lane = t & 63, wv = t >> 6;
  if (lane == 0) { sm[wv] = s; sm[wv + 4] = q; }
  __syncthreads();
  s = sm[0] + sm[1] + sm[2] + sm[3];
  q = sm[4] + sm[5] + sm[6] + sm[7];
  float mu = s * (1.0f / H);
  float var = q * (1.0f / H) - mu * mu;
  float rs = rsqrtf(var + 1e-5f);
  const float4* wr = reinterpret_cast<const float4*>(w);
  const float4* br = reinterpret_cast<const float4*>(b);
  float4 w0 = wr[t * 2], w1v = wr[t * 2 + 1], b0 = br[t * 2], b1v = br[t * 2 + 1];
  short8 pk;
  pk[0] = (short)f2bf((v0.x - mu) * rs * w0.x + b0.x);
  pk[1] = (short)f2bf((v0.y - mu) * rs * w0.y + b0.y);
  pk[2] = (short)f2bf((v0.z - mu) * rs * w0.z + b0.z);
  pk[3] = (short)f2bf((v0.w - mu) * rs * w0.w + b0.w);
  pk[4] = (short)f2bf((v1.x - mu) * rs * w1v.x + b1v.x);
  pk[5] = (short)f2bf((v1.y - mu) * rs * w1v.y + b1v.y);
  pk[6] = (short)f2bf((v1.z - mu) * rs * w1v.z + b1v.z);
  pk[7] = (short)f2bf((v1.w - mu) * rs * w1v.w + b1v.w);
  *reinterpret_cast<short8*>(out + (size_t)row * H + t * 8) = pk;
}

// out = res + p0 + p1 + bias (fp32)
__global__ __launch_bounds__(256) void combine2_kernel(
    const float* __restrict__ res, const float* __restrict__ p0,
    const float* __restrict__ p1, const float* __restrict__ bias,
    float* __restrict__ out) {
  size_t i = (size_t)blockIdx.x * 256 + threadIdx.x;
  float4 a = reinterpret_cast<const float4*>(res)[i];
  float4 c0 = reinterpret_cast<const float4*>(p0)[i];
  float4 c1 = reinterpret_cast<const float4*>(p1)[i];
  int col = (int)((i * 4) & (H - 1));
  float4 bb = *reinterpret_cast<const float4*>(bias + col);
  float4 o;
  o.x = a.x + c0.x + c1.x + bb.x;
  o.y = a.y + c0.y + c1.y + bb.y;
  o.z = a.z + c0.z + c1.z + bb.z;
  o.w = a.w + c0.w + c1.w + bb.w;
  reinterpret_cast<float4*>(out)[i] = o;
}

// fused: xout = res + p0 + p1 + bias (fp32) ; lnout = bf16(LN(xout))
__global__ __launch_bounds__(256) void combine_ln_kernel(
    const float* __restrict__ res, const float* __restrict__ p0,
    const float* __restrict__ p1, const float* __restrict__ bias,
    const float* __restrict__ lw, const float* __restrict__ lb,
    float* __restrict__ xout, ushort* __restrict__ lnout) {
  int row = blockIdx.x, t = threadIdx.x;
  const float4* rr = reinterpret_cast<const float4*>(res + (size_t)row * H);
  const float4* r0 = reinterpret_cast<const float4*>(p0 + (size_t)row * H);
  const float4* r1 = reinterpret_cast<const float4*>(p1 + (size_t)row * H);
  const float4* bb = reinterpret_cast<const float4*>(bias);
  float4 a0 = rr[t * 2], a1 = rr[t * 2 + 1];
  float4 c0 = r0[t * 2], c1 = r0[t * 2 + 1];
  float4 d0 = r1[t * 2], d1 = r1[t * 2 + 1];
  float4 e0 = bb[t * 2], e1 = bb[t * 2 + 1];
  float4 v0, v1;
  v0.x = a0.x + c0.x + d0.x + e0.x;
  v0.y = a0.y + c0.y + d0.y + e0.y;
  v0.z = a0.z + c0.z + d0.z + e0.z;
  v0.w = a0.w + c0.w + d0.w + e0.w;
  v1.x = a1.x + c1.x + d1.x + e1.x;
  v1.y = a1.y + c1.y + d1.y + e1.y;
  v1.z = a1.z + c1.z + d1.z + e1.z;
  v1.w = a1.w + c1.w + d1.w + e1.w;
  float4* xo = reinterpret_cast<float4*>(xout + (size_t)row * H);
  xo[t * 2] = v0;
  xo[t * 2 + 1] = v1;
  float s = v0.x + v0.y + v0.z + v0.w + v1.x + v1.y + v1.z + v1.w;
  float q = v0.x * v0.x + v0.y * v0.y + v0.z * v0.z + v0.w * v0.w +
            v1.x * v1.x + v1.y * v1.y + v1.z * v1.z + v1.w * v1.w;
#pragma unroll
  for (int off = 32; off > 0; off >>= 1) {
    s += __shfl_down(s, off, 64);
    q += __shfl_down(q, off, 64);
  }
  __shared__ float sm[8];
  int lane = t & 63, wv = t >> 6;
  if (lane == 0) { sm[wv] = s; sm[wv + 4] = q; }
  __syncthreads();
  s = sm[0] + sm[1] + sm[2] + sm[3];
  q = sm[4] + sm[5] + sm[6] + sm[7];
  float mu = s * (1.0f / H);
  float var = q * (1.0f / H) - mu * mu;
  float rs = rsqrtf(var + 1e-5f);
  const float4* wr = reinterpret_cast<const float4*>(lw);
  const float4* br = reinterpret_cast<const float4*>(lb);
  float4 w0 = wr[t * 2], w1v = wr[t * 2 + 1], b0 = br[t * 2], b1v = br[t * 2 + 1];
  short8 pk;
  pk[0] = (short)f2bf((v0.x - mu) * rs * w0.x + b0.x);
  pk[1] = (short)f2bf((v0.y - mu) * rs * w0.y + b0.y);
  pk[2] = (short)f2bf((v0.z - mu) * rs * w0.z + b0.z);
  pk[3] = (short)f2bf((v0.w - mu) * rs * w0.w + b0.w);
  pk[4] = (short)f2bf((v1.x - mu) * rs * w1v.x + b1v.x);
  pk[5] = (short)f2bf((v1.y - mu) * rs * w1v.y + b1v.y);
  pk[6] = (short)f2bf((v1.z - mu) * rs * w1v.z + b1v.z);
  pk[7] = (short)f2bf((v1.w - mu) * rs * w1v.w + b1v.w);
  *reinterpret_cast<short8*>(lnout + (size_t)row * H + t * 8) = pk;
}

// ---------------- 256xBN 8-phase bf16 MFMA GEMM (round-11 best, 16x16x32) ----
// BN = NI*64. 8 waves (2Mx4N). LDS 2dbuf, granule XOR swizzle, linear dest +
// pre-swizzled SOURCE + per-lane read bases with compile-time offsets.
// Phase order Q00,Q01,Q10,Q11 with register reuse ({12,4,8,0} reads).
// vmcnt(NI) end-ph1, vmcnt(2) end-ph3 + prologue; never 0 mid-loop.
// MODE 0: QKV epilogue (Q,K row-major; V transposed into outbV[H][S]).
// MODE 1: bf16(gelu(acc+bias)). MODE 3: fp32 split-K partial.
template <int MODE, int NI>
__global__ __launch_bounds__(512, 2) void gemm256_kernel(
    const ushort* __restrict__ A, const ushort* __restrict__ Bt,
    const float* __restrict__ bias, const float* __restrict__ biasB,
    const float* __restrict__ biasC,
    ushort* __restrict__ outb, ushort* __restrict__ outbV,
    float* __restrict__ outf,
    int M, int N, int lda, int kbeg, int klen) {
  constexpr int BN = NI * 64;
  constexpr int NH0 = (NI + 1) / 2;
  constexpr int NH1 = NI - NH0;
  constexpr int BQ0 = (NI + 1) / 2;
  __shared__ __align__(16) ushort As[2][256 * 64];
  __shared__ __align__(16) ushort Bs[2][BN * 64];
  int tid = threadIdx.x, lane = tid & 63, w = tid >> 6;
  int lm = lane & 15, kg = lane >> 4;
  int wr = w >> 2, wc = w & 3;
  int gx = gridDim.x, nwg = gx * gridDim.y;
  int orig = blockIdx.y * gx + blockIdx.x;
  int wg = (orig & 7) * (nwg >> 3) + (orig >> 3);
  int m0 = (wg % gx) * 256, n0 = (wg / gx) * BN;
  int kb0 = kbeg + blockIdx.z * klen;

  f32x4 acc[8][NI] = {};

  const ushort* srcA[4];
  const ushort* srcB[NI];
  int dbase[4];
#pragma unroll
  for (int q = 0; q < 4; q++) {
    int g = q * 512 + tid;
    int row = g >> 3, gc = g & 7;
    int col = (gc ^ (row & 7)) << 3;
    srcA[q] = A + (size_t)(m0 + row) * lda + kb0 + col;
    if (q < NI) srcB[q] = Bt + (size_t)(n0 + row) * lda + kb0 + col;
    dbase[q] = (q * 512 + w * 64) * 8;
  }

  const ushort* aB0 = &As[0][(wr * 128 + lm) * 64 + ((kg ^ (lm & 7)) << 3)];
  const ushort* aB1 = &As[0][(wr * 128 + lm) * 64 + (((4 + kg) ^ (lm & 7)) << 3)];
  const ushort* bB0 = &Bs[0][(wc * 16 * NI + lm) * 64 + ((kg ^ (lm & 7)) << 3)];
  const ushort* bB1 = &Bs[0][(wc * 16 * NI + lm) * 64 + (((4 + kg) ^ (lm & 7)) << 3)];

  int nK = klen >> 6;
#pragma unroll
  for (int q = 0; q < NI; q++) gl_lds16(srcB[q], &Bs[0][dbase[q]]);
  gl_lds16(srcA[0], &As[0][dbase[0]]);
  gl_lds16(srcA[2], &As[0][dbase[2]]);
  gl_lds16(srcA[1], &As[0][dbase[1]]);
  gl_lds16(srcA[3], &As[0][dbase[3]]);
  asm volatile("s_waitcnt vmcnt(2)" ::: "memory");
  __builtin_amdgcn_s_barrier();

  for (int kt = 0; kt < nK; kt++) {
    int cur = kt & 1, nxt = cur ^ 1;
    bool hn = (kt + 1 < nK);
    int ko = (kt + 1) << 6;
    const ushort* a0 = aB0 + cur * 16384;
    const ushort* a1 = aB1 + cur * 16384;
    const ushort* b0 = bB0 + cur * (BN * 64);
    const ushort* b1 = bB1 + cur * (BN * 64);

    short8 af[4][2], bf0[NH0][2], bf1[NH0][2];

    // phase 0: read af(mh0) + bf0; MFMA Q(0,0)
#pragma unroll
    for (int i = 0; i < 4; i++) {
      af[i][0] = *reinterpret_cast<const short8*>(a0 + i * 1024);
      af[i][1] = *reinterpret_cast<const short8*>(a1 + i * 1024);
    }
#pragma unroll
    for (int n = 0; n < NH0; n++) {
      bf0[n][0] = *reinterpret_cast<const short8*>(b0 + n * 1024);
      bf0[n][1] = *reinterpret_cast<const short8*>(b1 + n * 1024);
    }
    if (hn) {
#pragma unroll
      for (int q = 0; q < BQ0; q++) gl_lds16(srcB[q] + ko, &Bs[nxt][dbase[q]]);
    }
    __builtin_amdgcn_s_barrier();
    __builtin_amdgcn_s_setprio(1);
#pragma unroll
    for (int i = 0; i < 4; i++)
#pragma unroll
      for (int n = 0; n < NH0; n++)
#pragma unroll
        for (int s = 0; s < 2; s++)
          acc[i][n] = __builtin_amdgcn_mfma_f32_16x16x32_bf16(af[i][s], bf0[n][s], acc[i][n], 0, 0, 0);
    __builtin_amdgcn_s_setprio(0);
    __builtin_amdgcn_s_barrier();

    // phase 1: read bf1; MFMA Q(0,1)
#pragma unroll
    for (int n = 0; n < NH1; n++) {
      bf1[n][0] = *reinterpret_cast<const short8*>(b0 + (NH0 + n) * 1024);
      bf1[n][1] = *reinterpret_cast<const short8*>(b1 + (NH0 + n) * 1024);
    }
    if (hn) {
#pragma unroll
      for (int q = BQ0; q < NI; q++) gl_lds16(srcB[q] + ko, &Bs[nxt][dbase[q]]);
    }
    __builtin_amdgcn_s_barrier();
    __builtin_amdgcn_s_setprio(1);
#pragma unroll
    for (int i = 0; i < 4; i++)
#pragma unroll
      for (int n = 0; n < NH1; n++)
#pragma unroll
        for (int s = 0; s < 2; s++)
          acc[i][NH0 + n] = __builtin_amdgcn_mfma_f32_16x16x32_bf16(af[i][s], bf1[n][s], acc[i][NH0 + n], 0, 0, 0);
    __builtin_amdgcn_s_setprio(0);
    if (hn) {
      if constexpr (NI == 4) asm volatile("s_waitcnt vmcnt(4)" ::: "memory");
      else if constexpr (NI == 3) asm volatile("s_waitcnt vmcnt(3)" ::: "memory");
      else asm volatile("s_waitcnt vmcnt(2)" ::: "memory");
    } else {
      asm volatile("s_waitcnt vmcnt(0)" ::: "memory");
    }
    __builtin_amdgcn_s_barrier();

    // phase 2: read af(mh1); MFMA Q(1,0) (bf0 reused)
#pragma unroll
    for (int i = 0; i < 4; i++) {
      af[i][0] = *reinterpret_cast<const short8*>(a0 + 4096 + i * 1024);
      af[i][1] = *reinterpret_cast<const short8*>(a1 + 4096 + i * 1024);
    }
    if (hn) {
      gl_lds16(srcA[0] + ko, &As[nxt][dbase[0]]);
      gl_lds16(srcA[2] + ko, &As[nxt][dbase[2]]);
    }
    __builtin_amdgcn_s_barrier();
    __builtin_amdgcn_s_setprio(1);
#pragma unroll
    for (int i = 0; i < 4; i++)
#pragma unroll
      for (int n = 0; n < NH0; n++)
#pragma unroll
        for (int s = 0; s < 2; s++)
          acc[4 + i][n] = __builtin_amdgcn_mfma_f32_16x16x32_bf16(af[i][s], bf0[n][s], acc[4 + i][n], 0, 0, 0);
    __builtin_amdgcn_s_setprio(0);
    __builtin_amdgcn_s_barrier();

    // phase 3: no reads; MFMA Q(1,1) (af1, bf1 reused)
    if (hn) {
      gl_lds16(srcA[1] + ko, &As[nxt][dbase[1]]);
      gl_lds16(srcA[3] + ko, &As[nxt][dbase[3]]);
    }
    __builtin_amdgcn_s_barrier();
    __builtin_amdgcn_s_setprio(1);
#pragma unroll
    for (int i = 0; i < 4; i++)
#pragma unroll
      for (int n = 0; n < NH1; n++)
#pragma unroll
        for (int s = 0; s < 2; s++)
          acc[4 + i][NH0 + n] = __builtin_amdgcn_mfma_f32_16x16x32_bf16(af[i][s], bf1[n][s], acc[4 + i][NH0 + n], 0, 0, 0);
    __builtin_amdgcn_s_setprio(0);
    if (hn) asm volatile("s_waitcnt vmcnt(2)" ::: "memory");
    __builtin_amdgcn_s_barrier();
  }

#pragma unroll
  for (int mi = 0; mi < 8; mi++) {
#pragma unroll
    for (int ni = 0; ni < NI; ni++) {
      int row0 = m0 + wr * 128 + mi * 16 + kg * 4;
      int col = n0 + wc * 16 * NI + ni * 16 + lm;
      f32x4 v4 = acc[mi][ni];
      if (MODE == 0) {
        if (col < 2 * H) {
          float bb = (col < H) ? bias[col] : biasB[col - H];
          float sc = (col < H) ? 0.125f : 1.0f;
          size_t base = (size_t)(col >> 11) * ((size_t)S * H) + (col & (H - 1));
#pragma unroll
          for (int r = 0; r < 4; r++)
            outb[base + (size_t)(row0 + r) * H] = f2bf((v4[r] + bb) * sc);
        } else {
          float bb = biasC[col - 2 * H];
          s16x4 pk;
#pragma unroll
          for (int r = 0; r < 4; r++) pk[r] = (short)f2bf(v4[r] + bb);
          *reinterpret_cast<s16x4*>(outbV + (size_t)(col - 2 * H) * S + row0) = pk;
        }
      } else if (MODE == 1) {
#pragma unroll
        for (int r = 0; r < 4; r++) {
          float t = v4[r] + bias[col];
          outb[(size_t)(row0 + r) * N + col] = f2bf(0.5f * t * (1.0f + erff(t * 0.70710678118f)));
        }
      } else {
#pragma unroll
        for (int r = 0; r < 4; r++)
          outf[(size_t)blockIdx.z * M * N + (size_t)(row0 + r) * N + col] = v4[r];
      }
    }
  }
}

// causal flash attention: 512 blocks (2/CU), one 128-row q-block per block.
// Pairing qb = z<8 ? z : 23-z makes linear IDs 256 apart sum to 17 tiles
// (balanced if co-resident). 8 waves x 16 q-rows; KVB=128 dbuf; defer-max.
__global__ __launch_bounds__(512, 4) void attn_kernel(
    const ushort* __restrict__ Q, const ushort* __restrict__ Kmat,
    const ushort* __restrict__ VT, ushort* __restrict__ ctx) {
  __shared__ __align__(16) ushort Ks[2][128 * 64];
  __shared__ __align__(16) ushort Vs[2][64 * 128];
  __shared__ __align__(16) ushort Ps[8 * 16 * 64];
  int h = blockIdx.x;
  int z = blockIdx.y;
  int qb = (z < 8) ? z : 23 - z;
  int tid = threadIdx.x, lane = tid & 63, w = tid >> 6;
  int lm = lane & 15, kg = lane >> 4;
  int nt = qb + 1;

  short8 qa[2];
#pragma unroll
  for (int ks = 0; ks < 2; ks++)
    qa[ks] = *reinterpret_cast<const short8*>(
        Q + (size_t)(qb * 128 + w * 16 + lm) * H + h * 64 + ks * 32 + kg * 8);

  float m_run[4], l_run[4];
  f32x4 o_acc[4] = {};
#pragma unroll
  for (int r = 0; r < 4; r++) { m_run[r] = -1e30f; l_run[r] = 0.f; }

  auto stage = [&](int kb, int buf) {
#pragma unroll
    for (int p = 0; p < 2; p++) {
      int gbase = p * 512 + w * 64;
      int gran = gbase + lane;
      int krow = gran >> 3, gk = gran & 7;
      gl_lds16(Kmat + (size_t)(kb * 128 + krow) * H + h * 64 + ((gk ^ (krow & 7)) << 3),
               &Ks[buf][gbase * 8]);
    }
#pragma unroll
    for (int p = 0; p < 2; p++) {
      int gbase = p * 512 + w * 64;
      int gran = gbase + lane;
      int vrow = gran >> 4, gv = gran & 15;
      gl_lds16(VT + (size_t)(h * 64 + vrow) * S + kb * 128 + ((gv ^ (vrow & 15)) << 3),
               &Vs[buf][gbase * 8]);
    }
  };

  stage(0, 0);
  __syncthreads();

  for (int t = 0; t < nt; t++) {
    int cur = t & 1;
    if (t + 1 < nt) stage(t + 1, cur ^ 1);
    bool diag = (t == nt - 1);

    f32x4 sacc[8] = {};
#pragma unroll
    for (int j = 0; j < 8; j++) {
      int krow = j * 16 + lm;
#pragma unroll
      for (int ks = 0; ks < 2; ks++) {
        short8 kf = *reinterpret_cast<const short8*>(
            &Ks[cur][krow * 64 + (((ks * 4 + kg) ^ (lm & 7)) << 3)]);
        sacc[j] = __builtin_amdgcn_mfma_f32_16x16x32_bf16(qa[ks], kf, sacc[j], 0, 0, 0);
      }
    }
    if (diag) {
#pragma unroll
      for (int j = 0; j < 8; j++)
#pragma unroll
        for (int r = 0; r < 4; r++)
          if (j * 16 + lm > w * 16 + kg * 4 + r) sacc[j][r] = -1e30f;
    }

#pragma unroll
    for (int r = 0; r < 4; r++) {
      float mx = sacc[0][r];
#pragma unroll
      for (int j = 1; j < 8; j++) mx = fmaxf(mx, sacc[j][r]);
      mx = fmaxf(mx, __shfl_xor(mx, 1, 64));
      mx = fmaxf(mx, __shfl_xor(mx, 2, 64));
      mx = fmaxf(mx, __shfl_xor(mx, 4, 64));
      mx = fmaxf(mx, __shfl_xor(mx, 8, 64));
      // defer-max: only rescale when tile max exceeds running max by > 8
      float mold = m_run[r];
      bool need = (mx - mold) > 8.0f;  // uniform within each 16-lane row group
      float mref = need ? mx : mold;   // mx > mold whenever need
      float ps = 0.f;
#pragma unroll
      for (int j = 0; j < 8; j++) {
        float p = __expf(sacc[j][r] - mref);
        sacc[j][r] = p;
        ps += p;
      }
      ps += __shfl_xor(ps, 1, 64);
      ps += __shfl_xor(ps, 2, 64);
      ps += __shfl_xor(ps, 4, 64);
      ps += __shfl_xor(ps, 8, 64);
      if (need) {
        float sc = __expf(mold - mx);
        m_run[r] = mx;
        l_run[r] = l_run[r] * sc + ps;
#pragma unroll
        for (int jd = 0; jd < 4; jd++) o_acc[jd][r] *= sc;
      } else {
        l_run[r] = l_run[r] + ps;
      }
    }

#pragma unroll
    for (int c = 0; c < 2; c++) {
#pragma unroll
      for (int jj = 0; jj < 4; jj++)
#pragma unroll
        for (int r = 0; r < 4; r++) {
          int rl = kg * 4 + r;
          int col = jj * 16 + lm;
          Ps[w * 1024 + rl * 64 + (((col >> 3) ^ (rl & 7)) << 3) + (col & 7)] =
              f2bf(sacc[c * 4 + jj][r]);
        }
      short8 pa[2];
#pragma unroll
      for (int ks = 0; ks < 2; ks++)
        pa[ks] = *reinterpret_cast<const short8*>(
            &Ps[w * 1024 + lm * 64 + (((ks * 4 + kg) ^ (lm & 7)) << 3)]);
#pragma unroll
      for (int jd = 0; jd < 4; jd++) {
        int d = jd * 16 + lm;
#pragma unroll
        for (int ks = 0; ks < 2; ks++) {
          short8 vf = *reinterpret_cast<const short8*>(
              &Vs[cur][d * 128 + (((c * 8 + ks * 4 + kg) ^ lm) << 3)]);
          o_acc[jd] = __builtin_amdgcn_mfma_f32_16x16x32_bf16(pa[ks], vf, o_acc[jd], 0, 0, 0);
        }
      }
    }
    __syncthreads();
  }

#pragma unroll
  for (int jd = 0; jd < 4; jd++)
#pragma unroll
    for (int r = 0; r < 4; r++)
      ctx[(size_t)(qb * 128 + w * 16 + kg * 4 + r) * H + h * 64 + jd * 16 + lm] =
          f2bf(o_acc[jd][r] / l_run[r]);
}

extern "C" void kernel_launch(void* const* d_in, const int* in_sizes, int n_in,
                              void* d_out, int out_size, void* d_ws, size_t ws_size,
                              hipStream_t stream) {
  const float* x = (const float*)d_in[0];
  const float* ln1w = (const float*)d_in[2];
  const float* ln1b = (const float*)d_in[3];
  const float* wq = (const float*)d_in[4];
  const float* bq = (const float*)d_in[5];
  const float* wk = (const float*)d_in[6];
  const float* bk = (const float*)d_in[7];
  const float* wv = (const float*)d_in[8];
  const float* bv = (const float*)d_in[9];
  const float* wo = (const float*)d_in[10];
  const float* bo = (const float*)d_in[11];
  const float* w1 = (const float*)d_in[12];
  const float* b1 = (const float*)d_in[13];
  const float* w2 = (const float*)d_in[14];
  const float* b2 = (const float*)d_in[15];
  const float* ln2w = (const float*)d_in[16];
  const float* ln2b = (const float*)d_in[17];
  float* out = (float*)d_out;

  char* ws = (char*)d_ws;
  const size_t MB = 1024 * 1024;
  const size_t SH = (size_t)S * H;
  ushort* WT_QKV = (ushort*)(ws);               // 0-24MB, dead after QKV gemm
  ushort* WT_O = (ushort*)(ws + 24 * MB);       // 24-32
  ushort* WT_1 = (ushort*)(ws + 32 * MB);       // 32-64, dead after MLP1
  ushort* WT_2 = (ushort*)(ws + 64 * MB);       // 64-96
  ushort* LNO = (ushort*)(ws + 96 * MB);        // 96-104
  ushort* QKVB = (ushort*)(ws + 104 * MB);      // Q,K: 104-120, dead after attn
  ushort* VTb = (ushort*)(ws + 128 * MB);       // V transposed [H][S]: 128-136
  ushort* CTX = (ushort*)(ws + 136 * MB);       // 136-144
  float* X1 = (float*)(ws + 144 * MB);          // 144-160
  ushort* MID = (ushort*)(ws);                  // 0-32 (over dead WT_QKV+WT_O)
  float* SPA = (float*)(ws + 104 * MB);         // attn-out partials {0,1}: 104-136
  float* SPM = (float*)(ws + 32 * MB);          // MLP2 partials {0,1}: 32-64 (over dead WT_1)

  transpose_all_kernel<<<12288, 256, 0, stream>>>(
      wq, wk, wv, wo, w1, w2, WT_QKV, WT_O, WT_1, WT_2);

  ln_kernel<<<S, 256, 0, stream>>>(x, ln1w, ln1b, LNO);

  // QKV: BN=192 -> 256 blocks; V written transposed directly into VTb
  gemm256_kernel<0, 3><<<dim3(S / 256, 3 * H / 192), 512, 0, stream>>>(
      LNO, WT_QKV, bq, bk, bv, QKVB, VTb, nullptr, S, 3 * H, H, 0, H);

  attn_kernel<<<dim3(NH, 16), 512, 0, stream>>>(QKVB, QKVB + SH, VTb, CTX);

  // attn-out: BN=128, split-K2 -> 256 blocks
  gemm256_kernel<3, 2><<<dim3(S / 256, H / 128, 2), 512, 0, stream>>>(
      CTX, WT_O, nullptr, nullptr, nullptr, nullptr, nullptr, SPA, S, H, H, 0, H / 2);
  combine_ln_kernel<<<S, 256, 0, stream>>>(x, SPA, SPA + SH, bo, ln2w, ln2b, X1, LNO);

  gemm256_kernel<1, 4><<<dim3(S / 256, DFF / 256), 512, 0, stream>>>(
      LNO, WT_1, b1, nullptr, nullptr, MID, nullptr, nullptr, S, DFF, H, 0, H);

  // MLP2: BN=128, split-K2 -> 256 blocks
  gemm256_kernel<3, 2><<<dim3(S / 256, H / 128, 2), 512, 0, stream>>>(
      MID, WT_2, nullptr, nullptr, nullptr, nullptr, nullptr, SPM, S, H, DFF, 0, DFF / 2);
  combine2_kernel<<<SH / 1024, 256, 0, stream>>>(X1, SPM, SPM + SH, b2, out);
}

// Round 14
// 385.052 us; speedup vs baseline: 1.0456x; 1.0456x over previous
//
#include <hip/hip_runtime.h>
#include <math.h>

#define H 2048
#define S 2048
#define NH 32
#define HD 64
#define DFF 8192

typedef __attribute__((ext_vector_type(4))) float f32x4;
typedef __attribute__((ext_vector_type(8))) short short8;
typedef __attribute__((ext_vector_type(4))) short s16x4;

static __device__ __forceinline__ ushort f2bf(float f) {
  unsigned u = __float_as_uint(f);
  u += 0x7fff + ((u >> 16) & 1);
  return (ushort)(u >> 16);
}

static __device__ __forceinline__ float bf2f(ushort u) {
  return __uint_as_float(((unsigned)u) << 16);
}

static __device__ __forceinline__ void gl_lds16(const ushort* g, ushort* l) {
  __builtin_amdgcn_global_load_lds(
      (__attribute__((address_space(1))) const void*)g,
      (__attribute__((address_space(3))) void*)l, 16, 0, 0);
}

// all six weight transposes (fp32 -> bf16, [K][N] -> [N][K]) in one flat launch
__global__ __launch_bounds__(256) void transpose_all_kernel(
    const float* __restrict__ wq, const float* __restrict__ wk,
    const float* __restrict__ wv, const float* __restrict__ wo,
    const float* __restrict__ w1, const float* __restrict__ w2,
    ushort* __restrict__ oQKV, ushort* __restrict__ oO,
    ushort* __restrict__ o1, ushort* __restrict__ o2) {
  __shared__ __align__(16) ushort tile[64][72];
  int id = blockIdx.x;
  const float* W;
  ushort* Wt;
  int K, N, bx, by;
  if (id < 4096) {
    int which = id >> 10, r = id & 1023;
    bx = r & 31; by = r >> 5; K = H; N = H;
    W = (which == 0) ? wq : (which == 1) ? wk : (which == 2) ? wv : wo;
    Wt = (which == 3) ? oO : oQKV + (size_t)which * H * H;
  } else if (id < 8192) {
    int r = id - 4096;
    bx = r & 127; by = r >> 7; K = H; N = DFF;
    W = w1; Wt = o1;
  } else {
    int r = id - 8192;
    bx = r & 31; by = r >> 5; K = DFF; N = H;
    W = w2; Wt = o2;
  }
  int n0 = bx * 64, k0 = by * 64;
  int t = threadIdx.x;
  int lk = t >> 4;
  int ln4 = (t & 15) * 4;
#pragma unroll
  for (int p = 0; p < 4; p++) {
    int k = p * 16 + lk;
    float4 v = *reinterpret_cast<const float4*>(&W[(size_t)(k0 + k) * N + n0 + ln4]);
    float vv[4] = {v.x, v.y, v.z, v.w};
#pragma unroll
    for (int i = 0; i < 4; i++) {
      int row = ln4 + i;
      int slot = ((k >> 3) ^ (row & 7));
      tile[row][(slot << 3) + (k & 7)] = f2bf(vv[i]);
    }
  }
  __syncthreads();
  int n = t >> 2;
  int kq = (t & 3) * 8;
#pragma unroll
  for (int p = 0; p < 2; p++) {
    int kk = kq + p * 32;
    int slot = ((kk >> 3) ^ (n & 7));
    short8 o = *reinterpret_cast<const short8*>(&tile[n][slot << 3]);
    *reinterpret_cast<short8*>(&Wt[(size_t)(n0 + n) * K + k0 + kk]) = o;
  }
}

// LayerNorm fp32 -> bf16
__global__ __launch_bounds__(256) void ln_kernel(
    const float* __restrict__ x, const float* __restrict__ w,
    const float* __restrict__ b, ushort* __restrict__ out) {
  int row = blockIdx.x, t = threadIdx.x;
  const float4* xr = reinterpret_cast<const float4*>(x + (size_t)row * H);
  float4 v0 = xr[t * 2], v1 = xr[t * 2 + 1];
  float s = v0.x + v0.y + v0.z + v0.w + v1.x + v1.y + v1.z + v1.w;
  float q = v0.x * v0.x + v0.y * v0.y + v0.z * v0.z + v0.w * v0.w +
            v1.x * v1.x + v1.y * v1.y + v1.z * v1.z + v1.w * v1.w;
#pragma unroll
  for (int off = 32; off > 0; off >>= 1) {
    s += __shfl_down(s, off, 64);
    q += __shfl_down(q, off, 64);
  }
  __shared__ float sm[8];
  int lane = t & 63, wv = t >> 6;
  if (lane == 0) { sm[wv] = s; sm[wv + 4] = q; }
  __syncthreads();
  s = sm[0] + sm[1] + sm[2] + sm[3];
  q = sm[4] + sm[5] + sm[6] + sm[7];
  float mu = s * (1.0f / H);
  float var = q * (1.0f / H) - mu * mu;
  float rs = rsqrtf(var + 1e-5f);
  const float4* wr = reinterpret_cast<const float4*>(w);
  const float4* br = reinterpret_cast<const float4*>(b);
  float4 w0 = wr[t * 2], w1v = wr[t * 2 + 1], b0 = br[t * 2], b1v = br[t * 2 + 1];
  short8 pk;
  pk[0] = (short)f2bf((v0.x - mu) * rs * w0.x + b0.x);
  pk[1] = (short)f2bf((v0.y - mu) * rs * w0.y + b0.y);
  pk[2] = (short)f2bf((v0.z - mu) * rs * w0.z + b0.z);
  pk[3] = (short)f2bf((v0.w - mu) * rs * w0.w + b0.w);
  pk[4] = (short)f2bf((v1.x - mu) * rs * w1v.x + b1v.x);
  pk[5] = (short)f2bf((v1.y - mu) * rs * w1v.y + b1v.y);
  pk[6] = (short)f2bf((v1.z - mu) * rs * w1v.z + b1v.z);
  pk[7] = (short)f2bf((v1.w - mu) * rs * w1v.w + b1v.w);
  *reinterpret_cast<short8*>(out + (size_t)row * H + t * 8) = pk;
}

// out = res + p0 + p1 + bias, p0/p1 bf16 partials
__global__ __launch_bounds__(256) void combine2_kernel(
    const float* __restrict__ res, const ushort* __restrict__ p0,
    const ushort* __restrict__ p1, const float* __restrict__ bias,
    float* __restrict__ out) {
  size_t i = (size_t)blockIdx.x * 256 + threadIdx.x;
  float4 a0 = reinterpret_cast<const float4*>(res)[i * 2];
  float4 a1 = reinterpret_cast<const float4*>(res)[i * 2 + 1];
  short8 c = reinterpret_cast<const short8*>(p0)[i];
  short8 d = reinterpret_cast<const short8*>(p1)[i];
  int col = (int)((i * 8) & (H - 1));
  float4 b0 = *reinterpret_cast<const float4*>(bias + col);
  float4 b1 = *reinterpret_cast<const float4*>(bias + col + 4);
  float4 o0, o1;
  o0.x = a0.x + bf2f((ushort)c[0]) + bf2f((ushort)d[0]) + b0.x;
  o0.y = a0.y + bf2f((ushort)c[1]) + bf2f((ushort)d[1]) + b0.y;
  o0.z = a0.z + bf2f((ushort)c[2]) + bf2f((ushort)d[2]) + b0.z;
  o0.w = a0.w + bf2f((ushort)c[3]) + bf2f((ushort)d[3]) + b0.w;
  o1.x = a1.x + bf2f((ushort)c[4]) + bf2f((ushort)d[4]) + b1.x;
  o1.y = a1.y + bf2f((ushort)c[5]) + bf2f((ushort)d[5]) + b1.y;
  o1.z = a1.z + bf2f((ushort)c[6]) + bf2f((ushort)d[6]) + b1.z;
  o1.w = a1.w + bf2f((ushort)c[7]) + bf2f((ushort)d[7]) + b1.w;
  reinterpret_cast<float4*>(out)[i * 2] = o0;
  reinterpret_cast<float4*>(out)[i * 2 + 1] = o1;
}

// fused: xout = res + p0 + p1 + bias (p0/p1 bf16) ; lnout = bf16(LN(xout))
__global__ __launch_bounds__(256) void combine_ln_kernel(
    const float* __restrict__ res, const ushort* __restrict__ p0,
    const ushort* __restrict__ p1, const float* __restrict__ bias,
    const float* __restrict__ lw, const float* __restrict__ lb,
    float* __restrict__ xout, ushort* __restrict__ lnout) {
  int row = blockIdx.x, t = threadIdx.x;
  const float4* rr = reinterpret_cast<const float4*>(res + (size_t)row * H);
  short8 c = *reinterpret_cast<const short8*>(p0 + (size_t)row * H + t * 8);
  short8 d = *reinterpret_cast<const short8*>(p1 + (size_t)row * H + t * 8);
  const float4* bb = reinterpret_cast<const float4*>(bias);
  float4 a0 = rr[t * 2], a1 = rr[t * 2 + 1];
  float4 e0 = bb[t * 2], e1 = bb[t * 2 + 1];
  float4 v0, v1;
  v0.x = a0.x + bf2f((ushort)c[0]) + bf2f((ushort)d[0]) + e0.x;
  v0.y = a0.y + bf2f((ushort)c[1]) + bf2f((ushort)d[1]) + e0.y;
  v0.z = a0.z + bf2f((ushort)c[2]) + bf2f((ushort)d[2]) + e0.z;
  v0.w = a0.w + bf2f((ushort)c[3]) + bf2f((ushort)d[3]) + e0.w;
  v1.x = a1.x + bf2f((ushort)c[4]) + bf2f((ushort)d[4]) + e1.x;
  v1.y = a1.y + bf2f((ushort)c[5]) + bf2f((ushort)d[5]) + e1.y;
  v1.z = a1.z + bf2f((ushort)c[6]) + bf2f((ushort)d[6]) + e1.z;
  v1.w = a1.w + bf2f((ushort)c[7]) + bf2f((ushort)d[7]) + e1.w;
  float4* xo = reinterpret_cast<float4*>(xout + (size_t)row * H);
  xo[t * 2] = v0;
  xo[t * 2 + 1] = v1;
  float s = v0.x + v0.y + v0.z + v0.w + v1.x + v1.y + v1.z + v1.w;
  float q = v0.x * v0.x + v0.y * v0.y + v0.z * v0.z + v0.w * v0.w +
            v1.x * v1.x + v1.y * v1.y + v1.z * v1.z + v1.w * v1.w;
#pragma unroll
  for (int off = 32; off > 0; off >>= 1) {
    s += __shfl_down(s, off, 64);
    q += __shfl_down(q, off, 64);
  }
  __shared__ float sm[8];
  int lane = t & 63, wv = t >> 6;
  if (lane == 0) { sm[wv] = s; sm[wv + 4] = q; }
  __syncthreads();
  s = sm[0] + sm[1] + sm[2] + sm[3];
  q = sm[4] + sm[5] + sm[6] + sm[7];
  float mu = s * (1.0f / H);
  float var = q * (1.0f / H) - mu * mu;
  float rs = rsqrtf(var + 1e-5f);
  const float4* wr = reinterpret_cast<const float4*>(lw);
  const float4* br = reinterpret_cast<const float4*>(lb);
  float4 w0 = wr[t * 2], w1v = wr[t * 2 + 1], b0 = br[t * 2], b1v = br[t * 2 + 1];
  short8 pk;
  pk[0] = (short)f2bf((v0.x - mu) * rs * w0.x + b0.x);
  pk[1] = (short)f2bf((v0.y - mu) * rs * w0.y + b0.y);
  pk[2] = (short)f2bf((v0.z - mu) * rs * w0.z + b0.z);
  pk[3] = (short)f2bf((v0.w - mu) * rs * w0.w + b0.w);
  pk[4] = (short)f2bf((v1.x - mu) * rs * w1v.x + b1v.x);
  pk[5] = (short)f2bf((v1.y - mu) * rs * w1v.y + b1v.y);
  pk[6] = (short)f2bf((v1.z - mu) * rs * w1v.z + b1v.z);
  pk[7] = (short)f2bf((v1.w - mu) * rs * w1v.w + b1v.w);
  *reinterpret_cast<short8*>(lnout + (size_t)row * H + t * 8) = pk;
}

// ---------------- 256xBN 8-phase bf16 MFMA GEMM (round-11 best, 16x16x32) ----
// BN = NI*64. 8 waves (2Mx4N). LDS 2dbuf, granule XOR swizzle, linear dest +
// pre-swizzled SOURCE + per-lane read bases with compile-time offsets.
// Phase order Q00,Q01,Q10,Q11 with register reuse ({12,4,8,0} reads).
// vmcnt(NI) end-ph1, vmcnt(2) end-ph3 + prologue; never 0 mid-loop.
// MODE 0: QKV epilogue (Q,K row-major; V transposed into outbV[H][S]).
// MODE 1: bf16(gelu(acc+bias)). MODE 3: bf16 split-K partial.
template <int MODE, int NI>
__global__ __launch_bounds__(512, 2) void gemm256_kernel(
    const ushort* __restrict__ A, const ushort* __restrict__ Bt,
    const float* __restrict__ bias, const float* __restrict__ biasB,
    const float* __restrict__ biasC,
    ushort* __restrict__ outb, ushort* __restrict__ outbV,
    int M, int N, int lda, int kbeg, int klen) {
  constexpr int BN = NI * 64;
  constexpr int NH0 = (NI + 1) / 2;
  constexpr int NH1 = NI - NH0;
  constexpr int BQ0 = (NI + 1) / 2;
  __shared__ __align__(16) ushort As[2][256 * 64];
  __shared__ __align__(16) ushort Bs[2][BN * 64];
  int tid = threadIdx.x, lane = tid & 63, w = tid >> 6;
  int lm = lane & 15, kg = lane >> 4;
  int wr = w >> 2, wc = w & 3;
  int gx = gridDim.x, nwg = gx * gridDim.y;
  int orig = blockIdx.y * gx + blockIdx.x;
  int wg = (orig & 7) * (nwg >> 3) + (orig >> 3);
  int m0 = (wg % gx) * 256, n0 = (wg / gx) * BN;
  int kb0 = kbeg + blockIdx.z * klen;

  f32x4 acc[8][NI] = {};

  const ushort* srcA[4];
  const ushort* srcB[NI];
  int dbase[4];
#pragma unroll
  for (int q = 0; q < 4; q++) {
    int g = q * 512 + tid;
    int row = g >> 3, gc = g & 7;
    int col = (gc ^ (row & 7)) << 3;
    srcA[q] = A + (size_t)(m0 + row) * lda + kb0 + col;
    if (q < NI) srcB[q] = Bt + (size_t)(n0 + row) * lda + kb0 + col;
    dbase[q] = (q * 512 + w * 64) * 8;
  }

  const ushort* aB0 = &As[0][(wr * 128 + lm) * 64 + ((kg ^ (lm & 7)) << 3)];
  const ushort* aB1 = &As[0][(wr * 128 + lm) * 64 + (((4 + kg) ^ (lm & 7)) << 3)];
  const ushort* bB0 = &Bs[0][(wc * 16 * NI + lm) * 64 + ((kg ^ (lm & 7)) << 3)];
  const ushort* bB1 = &Bs[0][(wc * 16 * NI + lm) * 64 + (((4 + kg) ^ (lm & 7)) << 3)];

  int nK = klen >> 6;
#pragma unroll
  for (int q = 0; q < NI; q++) gl_lds16(srcB[q], &Bs[0][dbase[q]]);
  gl_lds16(srcA[0], &As[0][dbase[0]]);
  gl_lds16(srcA[2], &As[0][dbase[2]]);
  gl_lds16(srcA[1], &As[0][dbase[1]]);
  gl_lds16(srcA[3], &As[0][dbase[3]]);
  asm volatile("s_waitcnt vmcnt(2)" ::: "memory");
  __builtin_amdgcn_s_barrier();

  for (int kt = 0; kt < nK; kt++) {
    int cur = kt & 1, nxt = cur ^ 1;
    bool hn = (kt + 1 < nK);
    int ko = (kt + 1) << 6;
    const ushort* a0 = aB0 + cur * 16384;
    const ushort* a1 = aB1 + cur * 16384;
    const ushort* b0 = bB0 + cur * (BN * 64);
    const ushort* b1 = bB1 + cur * (BN * 64);

    short8 af[4][2], bf0[NH0][2], bf1[NH0][2];

    // phase 0: read af(mh0) + bf0; MFMA Q(0,0)
#pragma unroll
    for (int i = 0; i < 4; i++) {
      af[i][0] = *reinterpret_cast<const short8*>(a0 + i * 1024);
      af[i][1] = *reinterpret_cast<const short8*>(a1 + i * 1024);
    }
#pragma unroll
    for (int n = 0; n < NH0; n++) {
      bf0[n][0] = *reinterpret_cast<const short8*>(b0 + n * 1024);
      bf0[n][1] = *reinterpret_cast<const short8*>(b1 + n * 1024);
    }
    if (hn) {
#pragma unroll
      for (int q = 0; q < BQ0; q++) gl_lds16(srcB[q] + ko, &Bs[nxt][dbase[q]]);
    }
    __builtin_amdgcn_s_barrier();
    __builtin_amdgcn_s_setprio(1);
#pragma unroll
    for (int i = 0; i < 4; i++)
#pragma unroll
      for (int n = 0; n < NH0; n++)
#pragma unroll
        for (int s = 0; s < 2; s++)
          acc[i][n] = __builtin_amdgcn_mfma_f32_16x16x32_bf16(af[i][s], bf0[n][s], acc[i][n], 0, 0, 0);
    __builtin_amdgcn_s_setprio(0);
    __builtin_amdgcn_s_barrier();

    // phase 1: read bf1; MFMA Q(0,1)
#pragma unroll
    for (int n = 0; n < NH1; n++) {
      bf1[n][0] = *reinterpret_cast<const short8*>(b0 + (NH0 + n) * 1024);
      bf1[n][1] = *reinterpret_cast<const short8*>(b1 + (NH0 + n) * 1024);
    }
    if (hn) {
#pragma unroll
      for (int q = BQ0; q < NI; q++) gl_lds16(srcB[q] + ko, &Bs[nxt][dbase[q]]);
    }
    __builtin_amdgcn_s_barrier();
    __builtin_amdgcn_s_setprio(1);
#pragma unroll
    for (int i = 0; i < 4; i++)
#pragma unroll
      for (int n = 0; n < NH1; n++)
#pragma unroll
        for (int s = 0; s < 2; s++)
          acc[i][NH0 + n] = __builtin_amdgcn_mfma_f32_16x16x32_bf16(af[i][s], bf1[n][s], acc[i][NH0 + n], 0, 0, 0);
    __builtin_amdgcn_s_setprio(0);
    if (hn) {
      if constexpr (NI == 4) asm volatile("s_waitcnt vmcnt(4)" ::: "memory");
      else if constexpr (NI == 3) asm volatile("s_waitcnt vmcnt(3)" ::: "memory");
      else asm volatile("s_waitcnt vmcnt(2)" ::: "memory");
    } else {
      asm volatile("s_waitcnt vmcnt(0)" ::: "memory");
    }
    __builtin_amdgcn_s_barrier();

    // phase 2: read af(mh1); MFMA Q(1,0) (bf0 reused)
#pragma unroll
    for (int i = 0; i < 4; i++) {
      af[i][0] = *reinterpret_cast<const short8*>(a0 + 4096 + i * 1024);
      af[i][1] = *reinterpret_cast<const short8*>(a1 + 4096 + i * 1024);
    }
    if (hn) {
      gl_lds16(srcA[0] + ko, &As[nxt][dbase[0]]);
      gl_lds16(srcA[2] + ko, &As[nxt][dbase[2]]);
    }
    __builtin_amdgcn_s_barrier();
    __builtin_amdgcn_s_setprio(1);
#pragma unroll
    for (int i = 0; i < 4; i++)
#pragma unroll
      for (int n = 0; n < NH0; n++)
#pragma unroll
        for (int s = 0; s < 2; s++)
          acc[4 + i][n] = __builtin_amdgcn_mfma_f32_16x16x32_bf16(af[i][s], bf0[n][s], acc[4 + i][n], 0, 0, 0);
    __builtin_amdgcn_s_setprio(0);
    __builtin_amdgcn_s_barrier();

    // phase 3: no reads; MFMA Q(1,1) (af1, bf1 reused)
    if (hn) {
      gl_lds16(srcA[1] + ko, &As[nxt][dbase[1]]);
      gl_lds16(srcA[3] + ko, &As[nxt][dbase[3]]);
    }
    __builtin_amdgcn_s_barrier();
    __builtin_amdgcn_s_setprio(1);
#pragma unroll
    for (int i = 0; i < 4; i++)
#pragma unroll
      for (int n = 0; n < NH1; n++)
#pragma unroll
        for (int s = 0; s < 2; s++)
          acc[4 + i][NH0 + n] = __builtin_amdgcn_mfma_f32_16x16x32_bf16(af[i][s], bf1[n][s], acc[4 + i][NH0 + n], 0, 0, 0);
    __builtin_amdgcn_s_setprio(0);
    if (hn) asm volatile("s_waitcnt vmcnt(2)" ::: "memory");
    __builtin_amdgcn_s_barrier();
  }

#pragma unroll
  for (int mi = 0; mi < 8; mi++) {
#pragma unroll
    for (int ni = 0; ni < NI; ni++) {
      int row0 = m0 + wr * 128 + mi * 16 + kg * 4;
      int col = n0 + wc * 16 * NI + ni * 16 + lm;
      f32x4 v4 = acc[mi][ni];
      if (MODE == 0) {
        if (col < 2 * H) {
          float bb = (col < H) ? bias[col] : biasB[col - H];
          float sc = (col < H) ? 0.125f : 1.0f;
          size_t base = (size_t)(col >> 11) * ((size_t)S * H) + (col & (H - 1));
#pragma unroll
          for (int r = 0; r < 4; r++)
            outb[base + (size_t)(row0 + r) * H] = f2bf((v4[r] + bb) * sc);
        } else {
          float bb = biasC[col - 2 * H];
          s16x4 pk;
#pragma unroll
          for (int r = 0; r < 4; r++) pk[r] = (short)f2bf(v4[r] + bb);
          *reinterpret_cast<s16x4*>(outbV + (size_t)(col - 2 * H) * S + row0) = pk;
        }
      } else if (MODE == 1) {
#pragma unroll
        for (int r = 0; r < 4; r++) {
          float t = v4[r] + bias[col];
          outb[(size_t)(row0 + r) * N + col] = f2bf(0.5f * t * (1.0f + erff(t * 0.70710678118f)));
        }
      } else {
#pragma unroll
        for (int r = 0; r < 4; r++)
          outb[(size_t)blockIdx.z * M * N + (size_t)(row0 + r) * N + col] = f2bf(v4[r]);
      }
    }
  }
}

// causal flash attention, folded q-pair scheduling (round-11 best).
// Block (h, x): q-blocks {x, 15-x} of 128 rows; 8 waves x 16 q-rows; KVB=128 dbuf.
__global__ __launch_bounds__(512) void attn_kernel(
    const ushort* __restrict__ Q, const ushort* __restrict__ Kmat,
    const ushort* __restrict__ VT, ushort* __restrict__ ctx) {
  __shared__ __align__(16) ushort Ks[2][128 * 64];
  __shared__ __align__(16) ushort Vs[2][64 * 128];
  __shared__ __align__(16) ushort Ps[8 * 16 * 64];
  int h = blockIdx.x;
  int x = blockIdx.y;
  int tid = threadIdx.x, lane = tid & 63, w = tid >> 6;
  int lm = lane & 15, kg = lane >> 4;

  int qbA = x, qbB = 15 - x;
  int tA = x + 1;
  const int nt = 17;

  short8 qa[2];
#pragma unroll
  for (int ks = 0; ks < 2; ks++)
    qa[ks] = *reinterpret_cast<const short8*>(
        Q + (size_t)(qbA * 128 + w * 16 + lm) * H + h * 64 + ks * 32 + kg * 8);

  float m_run[4], l_run[4];
  f32x4 o_acc[4] = {};
#pragma unroll
  for (int r = 0; r < 4; r++) { m_run[r] = -1e30f; l_run[r] = 0.f; }

  auto stage = [&](int kb, int buf) {
#pragma unroll
    for (int p = 0; p < 2; p++) {
      int gbase = p * 512 + w * 64;
      int gran = gbase + lane;
      int krow = gran >> 3, gk = gran & 7;
      gl_lds16(Kmat + (size_t)(kb * 128 + krow) * H + h * 64 + ((gk ^ (krow & 7)) << 3),
               &Ks[buf][gbase * 8]);
    }
#pragma unroll
    for (int p = 0; p < 2; p++) {
      int gbase = p * 512 + w * 64;
      int gran = gbase + lane;
      int vrow = gran >> 4, gv = gran & 15;
      gl_lds16(VT + (size_t)(h * 64 + vrow) * S + kb * 128 + ((gv ^ (vrow & 15)) << 3),
               &Vs[buf][gbase * 8]);
    }
  };

  stage(0, 0);
  __syncthreads();

  for (int t = 0; t < nt; t++) {
    int cur = t & 1;
    if (t + 1 < nt) {
      int tn = t + 1;
      stage((tn < tA) ? tn : tn - tA, cur ^ 1);
    }
    bool diag = (t == tA - 1) || (t == nt - 1);

    f32x4 sacc[8] = {};
#pragma unroll
    for (int j = 0; j < 8; j++) {
      int krow = j * 16 + lm;
#pragma unroll
      for (int ks = 0; ks < 2; ks++) {
        short8 kf = *reinterpret_cast<const short8*>(
            &Ks[cur][krow * 64 + (((ks * 4 + kg) ^ (lm & 7)) << 3)]);
        sacc[j] = __builtin_amdgcn_mfma_f32_16x16x32_bf16(qa[ks], kf, sacc[j], 0, 0, 0);
      }
    }
    if (diag) {
#pragma unroll
      for (int j = 0; j < 8; j++)
#pragma unroll
        for (int r = 0; r < 4; r++)
          if (j * 16 + lm > w * 16 + kg * 4 + r) sacc[j][r] = -1e30f;
    }

#pragma unroll
    for (int r = 0; r < 4; r++) {
      float mx = sacc[0][r];
#pragma unroll
      for (int j = 1; j < 8; j++) mx = fmaxf(mx, sacc[j][r]);
      mx = fmaxf(mx, __shfl_xor(mx, 1, 64));
      mx = fmaxf(mx, __shfl_xor(mx, 2, 64));
      mx = fmaxf(mx, __shfl_xor(mx, 4, 64));
      mx = fmaxf(mx, __shfl_xor(mx, 8, 64));
      float mnew = fmaxf(m_run[r], mx);
      float sc = __expf(m_run[r] - mnew);
      m_run[r] = mnew;
      float ps = 0.f;
#pragma unroll
      for (int j = 0; j < 8; j++) {
        float p = __expf(sacc[j][r] - mnew);
        sacc[j][r] = p;
        ps += p;
      }
      ps += __shfl_xor(ps, 1, 64);
      ps += __shfl_xor(ps, 2, 64);
      ps += __shfl_xor(ps, 4, 64);
      ps += __shfl_xor(ps, 8, 64);
      l_run[r] = l_run[r] * sc + ps;
#pragma unroll
      for (int jd = 0; jd < 4; jd++) o_acc[jd][r] *= sc;
    }

#pragma unroll
    for (int c = 0; c < 2; c++) {
#pragma unroll
      for (int jj = 0; jj < 4; jj++)
#pragma unroll
        for (int r = 0; r < 4; r++) {
          int rl = kg * 4 + r;
          int col = jj * 16 + lm;
          Ps[w * 1024 + rl * 64 + (((col >> 3) ^ (rl & 7)) << 3) + (col & 7)] =
              f2bf(sacc[c * 4 + jj][r]);
        }
      short8 pa[2];
#pragma unroll
      for (int ks = 0; ks < 2; ks++)
        pa[ks] = *reinterpret_cast<const short8*>(
            &Ps[w * 1024 + lm * 64 + (((ks * 4 + kg) ^ (lm & 7)) << 3)]);
#pragma unroll
      for (int jd = 0; jd < 4; jd++) {
        int d = jd * 16 + lm;
#pragma unroll
        for (int ks = 0; ks < 2; ks++) {
          short8 vf = *reinterpret_cast<const short8*>(
              &Vs[cur][d * 128 + (((c * 8 + ks * 4 + kg) ^ lm) << 3)]);
          o_acc[jd] = __builtin_amdgcn_mfma_f32_16x16x32_bf16(pa[ks], vf, o_acc[jd], 0, 0, 0);
        }
      }
    }

    if (t == tA - 1) {
#pragma unroll
      for (int jd = 0; jd < 4; jd++)
#pragma unroll
        for (int r = 0; r < 4; r++)
          ctx[(size_t)(qbA * 128 + w * 16 + kg * 4 + r) * H + h * 64 + jd * 16 + lm] =
              f2bf(o_acc[jd][r] / l_run[r]);
#pragma unroll
      for (int r = 0; r < 4; r++) { m_run[r] = -1e30f; l_run[r] = 0.f; }
#pragma unroll
      for (int jd = 0; jd < 4; jd++) o_acc[jd] = f32x4{0.f, 0.f, 0.f, 0.f};
#pragma unroll
      for (int ks = 0; ks < 2; ks++)
        qa[ks] = *reinterpret_cast<const short8*>(
            Q + (size_t)(qbB * 128 + w * 16 + lm) * H + h * 64 + ks * 32 + kg * 8);
    }
    __syncthreads();
  }

#pragma unroll
  for (int jd = 0; jd < 4; jd++)
#pragma unroll
    for (int r = 0; r < 4; r++)
      ctx[(size_t)(qbB * 128 + w * 16 + kg * 4 + r) * H + h * 64 + jd * 16 + lm] =
          f2bf(o_acc[jd][r] / l_run[r]);
}

extern "C" void kernel_launch(void* const* d_in, const int* in_sizes, int n_in,
                              void* d_out, int out_size, void* d_ws, size_t ws_size,
                              hipStream_t stream) {
  const float* x = (const float*)d_in[0];
  const float* ln1w = (const float*)d_in[2];
  const float* ln1b = (const float*)d_in[3];
  const float* wq = (const float*)d_in[4];
  const float* bq = (const float*)d_in[5];
  const float* wk = (const float*)d_in[6];
  const float* bk = (const float*)d_in[7];
  const float* wv = (const float*)d_in[8];
  const float* bv = (const float*)d_in[9];
  const float* wo = (const float*)d_in[10];
  const float* bo = (const float*)d_in[11];
  const float* w1 = (const float*)d_in[12];
  const float* b1 = (const float*)d_in[13];
  const float* w2 = (const float*)d_in[14];
  const float* b2 = (const float*)d_in[15];
  const float* ln2w = (const float*)d_in[16];
  const float* ln2b = (const float*)d_in[17];
  float* out = (float*)d_out;

  char* ws = (char*)d_ws;
  const size_t MB = 1024 * 1024;
  const size_t SH = (size_t)S * H;
  ushort* WT_QKV = (ushort*)(ws);               // 0-24MB, dead after QKV gemm
  ushort* WT_O = (ushort*)(ws + 24 * MB);       // 24-32
  ushort* WT_1 = (ushort*)(ws + 32 * MB);       // 32-64, dead after MLP1
  ushort* WT_2 = (ushort*)(ws + 64 * MB);       // 64-96
  ushort* LNO = (ushort*)(ws + 96 * MB);        // 96-104
  ushort* QKVB = (ushort*)(ws + 104 * MB);      // Q,K: 104-120, dead after attn
  ushort* VTb = (ushort*)(ws + 128 * MB);       // V transposed [H][S]: 128-136
  ushort* CTX = (ushort*)(ws + 136 * MB);       // 136-144
  float* X1 = (float*)(ws + 144 * MB);          // 144-160
  ushort* MID = (ushort*)(ws);                  // 0-32 (over dead WT_QKV+WT_O)
  ushort* SPA = (ushort*)(ws + 104 * MB);       // attn-out bf16 partials {0,1}: 104-120
  ushort* SPM = (ushort*)(ws + 32 * MB);        // MLP2 bf16 partials {0,1}: 32-48 (over dead WT_1)

  transpose_all_kernel<<<12288, 256, 0, stream>>>(
      wq, wk, wv, wo, w1, w2, WT_QKV, WT_O, WT_1, WT_2);

  ln_kernel<<<S, 256, 0, stream>>>(x, ln1w, ln1b, LNO);

  // QKV: BN=192 -> 256 blocks; V written transposed directly into VTb
  gemm256_kernel<0, 3><<<dim3(S / 256, 3 * H / 192), 512, 0, stream>>>(
      LNO, WT_QKV, bq, bk, bv, QKVB, VTb, S, 3 * H, H, 0, H);

  attn_kernel<<<dim3(NH, 8), 512, 0, stream>>>(QKVB, QKVB + SH, VTb, CTX);

  // attn-out: BN=128, split-K2 -> 256 blocks, bf16 partials
  gemm256_kernel<3, 2><<<dim3(S / 256, H / 128, 2), 512, 0, stream>>>(
      CTX, WT_O, nullptr, nullptr, nullptr, SPA, nullptr, S, H, H, 0, H / 2);
  combine_ln_kernel<<<S, 256, 0, stream>>>(x, SPA, SPA + SH, bo, ln2w, ln2b, X1, LNO);

  gemm256_kernel<1, 4><<<dim3(S / 256, DFF / 256), 512, 0, stream>>>(
      LNO, WT_1, b1, nullptr, nullptr, MID, nullptr, S, DFF, H, 0, H);

  // MLP2: BN=128, split-K2 -> 256 blocks, bf16 partials
  gemm256_kernel<3, 2><<<dim3(S / 256, H / 128, 2), 512, 0, stream>>>(
      MID, WT_2, nullptr, nullptr, nullptr, SPM, nullptr, S, H, DFF, 0, DFF / 2);
  combine2_kernel<<<SH / 2048, 256, 0, stream>>>(X1, SPM, SPM + SH, b2, out);
}

// Round 15
// 369.421 us; speedup vs baseline: 1.0899x; 1.0423x over previous
//
#include <hip/hip_runtime.h>
#include <math.h>

#define H 2048
#define S 2048
#define NH 32
#define HD 64
#define DFF 8192

typedef __attribute__((ext_vector_type(4))) float f32x4;
typedef __attribute__((ext_vector_type(8))) short short8;
typedef __attribute__((ext_vector_type(4))) short s16x4;

static __device__ __forceinline__ ushort f2bf(float f) {
  unsigned u = __float_as_uint(f);
  u += 0x7fff + ((u >> 16) & 1);
  return (ushort)(u >> 16);
}

static __device__ __forceinline__ float bf2f(ushort u) {
  return __uint_as_float(((unsigned)u) << 16);
}

static __device__ __forceinline__ void gl_lds16(const ushort* g, ushort* l) {
  __builtin_amdgcn_global_load_lds(
      (__attribute__((address_space(1))) const void*)g,
      (__attribute__((address_space(3))) void*)l, 16, 0, 0);
}

// all six weight transposes (fp32 -> bf16, [K][N] -> [N][K]) in one flat launch
__global__ __launch_bounds__(256) void transpose_all_kernel(
    const float* __restrict__ wq, const float* __restrict__ wk,
    const float* __restrict__ wv, const float* __restrict__ wo,
    const float* __restrict__ w1, const float* __restrict__ w2,
    ushort* __restrict__ oQKV, ushort* __restrict__ oO,
    ushort* __restrict__ o1, ushort* __restrict__ o2) {
  __shared__ __align__(16) ushort tile[64][72];
  int id = blockIdx.x;
  const float* W;
  ushort* Wt;
  int K, N, bx, by;
  if (id < 4096) {
    int which = id >> 10, r = id & 1023;
    bx = r & 31; by = r >> 5; K = H; N = H;
    W = (which == 0) ? wq : (which == 1) ? wk : (which == 2) ? wv : wo;
    Wt = (which == 3) ? oO : oQKV + (size_t)which * H * H;
  } else if (id < 8192) {
    int r = id - 4096;
    bx = r & 127; by = r >> 7; K = H; N = DFF;
    W = w1; Wt = o1;
  } else {
    int r = id - 8192;
    bx = r & 31; by = r >> 5; K = DFF; N = H;
    W = w2; Wt = o2;
  }
  int n0 = bx * 64, k0 = by * 64;
  int t = threadIdx.x;
  int lk = t >> 4;
  int ln4 = (t & 15) * 4;
#pragma unroll
  for (int p = 0; p < 4; p++) {
    int k = p * 16 + lk;
    float4 v = *reinterpret_cast<const float4*>(&W[(size_t)(k0 + k) * N + n0 + ln4]);
    float vv[4] = {v.x, v.y, v.z, v.w};
#pragma unroll
    for (int i = 0; i < 4; i++) {
      int row = ln4 + i;
      int slot = ((k >> 3) ^ (row & 7));
      tile[row][(slot << 3) + (k & 7)] = f2bf(vv[i]);
    }
  }
  __syncthreads();
  int n = t >> 2;
  int kq = (t & 3) * 8;
#pragma unroll
  for (int p = 0; p < 2; p++) {
    int kk = kq + p * 32;
    int slot = ((kk >> 3) ^ (n & 7));
    short8 o = *reinterpret_cast<const short8*>(&tile[n][slot << 3]);
    *reinterpret_cast<short8*>(&Wt[(size_t)(n0 + n) * K + k0 + kk]) = o;
  }
}

// LayerNorm fp32 -> bf16
__global__ __launch_bounds__(256) void ln_kernel(
    const float* __restrict__ x, const float* __restrict__ w,
    const float* __restrict__ b, ushort* __restrict__ out) {
  int row = blockIdx.x, t = threadIdx.x;
  const float4* xr = reinterpret_cast<const float4*>(x + (size_t)row * H);
  float4 v0 = xr[t * 2], v1 = xr[t * 2 + 1];
  float s = v0.x + v0.y + v0.z + v0.w + v1.x + v1.y + v1.z + v1.w;
  float q = v0.x * v0.x + v0.y * v0.y + v0.z * v0.z + v0.w * v0.w +
            v1.x * v1.x + v1.y * v1.y + v1.z * v1.z + v1.w * v1.w;
#pragma unroll
  for (int off = 32; off > 0; off >>= 1) {
    s += __shfl_down(s, off, 64);
    q += __shfl_down(q, off, 64);
  }
  __shared__ float sm[8];
  int lane = t & 63, wv = t >> 6;
  if (lane == 0) { sm[wv] = s; sm[wv + 4] = q; }
  __syncthreads();
  s = sm[0] + sm[1] + sm[2] + sm[3];
  q = sm[4] + sm[5] + sm[6] + sm[7];
  float mu = s * (1.0f / H);
  float var = q * (1.0f / H) - mu * mu;
  float rs = rsqrtf(var + 1e-5f);
  const float4* wr = reinterpret_cast<const float4*>(w);
  const float4* br = reinterpret_cast<const float4*>(b);
  float4 w0 = wr[t * 2], w1v = wr[t * 2 + 1], b0 = br[t * 2], b1v = br[t * 2 + 1];
  short8 pk;
  pk[0] = (short)f2bf((v0.x - mu) * rs * w0.x + b0.x);
  pk[1] = (short)f2bf((v0.y - mu) * rs * w0.y + b0.y);
  pk[2] = (short)f2bf((v0.z - mu) * rs * w0.z + b0.z);
  pk[3] = (short)f2bf((v0.w - mu) * rs * w0.w + b0.w);
  pk[4] = (short)f2bf((v1.x - mu) * rs * w1v.x + b1v.x);
  pk[5] = (short)f2bf((v1.y - mu) * rs * w1v.y + b1v.y);
  pk[6] = (short)f2bf((v1.z - mu) * rs * w1v.z + b1v.z);
  pk[7] = (short)f2bf((v1.w - mu) * rs * w1v.w + b1v.w);
  *reinterpret_cast<short8*>(out + (size_t)row * H + t * 8) = pk;
}

// out = res + p0 + p1 + bias, p0/p1 bf16 partials
__global__ __launch_bounds__(256) void combine2_kernel(
    const float* __restrict__ res, const ushort* __restrict__ p0,
    const ushort* __restrict__ p1, const float* __restrict__ bias,
    float* __restrict__ out) {
  size_t i = (size_t)blockIdx.x * 256 + threadIdx.x;
  float4 a0 = reinterpret_cast<const float4*>(res)[i * 2];
  float4 a1 = reinterpret_cast<const float4*>(res)[i * 2 + 1];
  short8 c = reinterpret_cast<const short8*>(p0)[i];
  short8 d = reinterpret_cast<const short8*>(p1)[i];
  int col = (int)((i * 8) & (H - 1));
  float4 b0 = *reinterpret_cast<const float4*>(bias + col);
  float4 b1 = *reinterpret_cast<const float4*>(bias + col + 4);
  float4 o0, o1;
  o0.x = a0.x + bf2f((ushort)c[0]) + bf2f((ushort)d[0]) + b0.x;
  o0.y = a0.y + bf2f((ushort)c[1]) + bf2f((ushort)d[1]) + b0.y;
  o0.z = a0.z + bf2f((ushort)c[2]) + bf2f((ushort)d[2]) + b0.z;
  o0.w = a0.w + bf2f((ushort)c[3]) + bf2f((ushort)d[3]) + b0.w;
  o1.x = a1.x + bf2f((ushort)c[4]) + bf2f((ushort)d[4]) + b1.x;
  o1.y = a1.y + bf2f((ushort)c[5]) + bf2f((ushort)d[5]) + b1.y;
  o1.z = a1.z + bf2f((ushort)c[6]) + bf2f((ushort)d[6]) + b1.z;
  o1.w = a1.w + bf2f((ushort)c[7]) + bf2f((ushort)d[7]) + b1.w;
  reinterpret_cast<float4*>(out)[i * 2] = o0;
  reinterpret_cast<float4*>(out)[i * 2 + 1] = o1;
}

// fused: xout = res + p0 + p1 + bias (p0/p1 bf16) ; lnout = bf16(LN(xout))
__global__ __launch_bounds__(256) void combine_ln_kernel(
    const float* __restrict__ res, const ushort* __restrict__ p0,
    const ushort* __restrict__ p1, const float* __restrict__ bias,
    const float* __restrict__ lw, const float* __restrict__ lb,
    float* __restrict__ xout, ushort* __restrict__ lnout) {
  int row = blockIdx.x, t = threadIdx.x;
  const float4* rr = reinterpret_cast<const float4*>(res + (size_t)row * H);
  short8 c = *reinterpret_cast<const short8*>(p0 + (size_t)row * H + t * 8);
  short8 d = *reinterpret_cast<const short8*>(p1 + (size_t)row * H + t * 8);
  const float4* bb = reinterpret_cast<const float4*>(bias);
  float4 a0 = rr[t * 2], a1 = rr[t * 2 + 1];
  float4 e0 = bb[t * 2], e1 = bb[t * 2 + 1];
  float4 v0, v1;
  v0.x = a0.x + bf2f((ushort)c[0]) + bf2f((ushort)d[0]) + e0.x;
  v0.y = a0.y + bf2f((ushort)c[1]) + bf2f((ushort)d[1]) + e0.y;
  v0.z = a0.z + bf2f((ushort)c[2]) + bf2f((ushort)d[2]) + e0.z;
  v0.w = a0.w + bf2f((ushort)c[3]) + bf2f((ushort)d[3]) + e0.w;
  v1.x = a1.x + bf2f((ushort)c[4]) + bf2f((ushort)d[4]) + e1.x;
  v1.y = a1.y + bf2f((ushort)c[5]) + bf2f((ushort)d[5]) + e1.y;
  v1.z = a1.z + bf2f((ushort)c[6]) + bf2f((ushort)d[6]) + e1.z;
  v1.w = a1.w + bf2f((ushort)c[7]) + bf2f((ushort)d[7]) + e1.w;
  float4* xo = reinterpret_cast<float4*>(xout + (size_t)row * H);
  xo[t * 2] = v0;
  xo[t * 2 + 1] = v1;
  float s = v0.x + v0.y + v0.z + v0.w + v1.x + v1.y + v1.z + v1.w;
  float q = v0.x * v0.x + v0.y * v0.y + v0.z * v0.z + v0.w * v0.w +
            v1.x * v1.x + v1.y * v1.y + v1.z * v1.z + v1.w * v1.w;
#pragma unroll
  for (int off = 32; off > 0; off >>= 1) {
    s += __shfl_down(s, off, 64);
    q += __shfl_down(q, off, 64);
  }
  __shared__ float sm[8];
  int lane = t & 63, wv = t >> 6;
  if (lane == 0) { sm[wv] = s; sm[wv + 4] = q; }
  __syncthreads();
  s = sm[0] + sm[1] + sm[2] + sm[3];
  q = sm[4] + sm[5] + sm[6] + sm[7];
  float mu = s * (1.0f / H);
  float var = q * (1.0f / H) - mu * mu;
  float rs = rsqrtf(var + 1e-5f);
  const float4* wr = reinterpret_cast<const float4*>(lw);
  const float4* br = reinterpret_cast<const float4*>(lb);
  float4 w0 = wr[t * 2], w1v = wr[t * 2 + 1], b0 = br[t * 2], b1v = br[t * 2 + 1];
  short8 pk;
  pk[0] = (short)f2bf((v0.x - mu) * rs * w0.x + b0.x);
  pk[1] = (short)f2bf((v0.y - mu) * rs * w0.y + b0.y);
  pk[2] = (short)f2bf((v0.z - mu) * rs * w0.z + b0.z);
  pk[3] = (short)f2bf((v0.w - mu) * rs * w0.w + b0.w);
  pk[4] = (short)f2bf((v1.x - mu) * rs * w1v.x + b1v.x);
  pk[5] = (short)f2bf((v1.y - mu) * rs * w1v.y + b1v.y);
  pk[6] = (short)f2bf((v1.z - mu) * rs * w1v.z + b1v.z);
  pk[7] = (short)f2bf((v1.w - mu) * rs * w1v.w + b1v.w);
  *reinterpret_cast<short8*>(lnout + (size_t)row * H + t * 8) = pk;
}

// ---------------- 256xBN bf16 MFMA GEMM, merged 2-phase (4 barriers/K-tile) --
// BN = NI*64. 8 waves (2Mx4N). LDS 2dbuf, granule XOR swizzle, linear dest +
// pre-swizzled SOURCE + per-lane read bases with compile-time offsets.
// Phase A: read af(mh0)+ALL bf (16 reads), stage next B, bar, 32 MFMA,
//   vmcnt(NI) [per-wave drains its own A1,A3; barrier publishes cross-wave], bar.
// Phase B: read af(mh1) (8), stage next A0,A2,A1,A3, bar, 32 MFMA,
//   vmcnt(2) [drains next tile's B+A0,A2], bar.
// MODE 0: QKV epilogue (Q,K row-major; V transposed into outbV[H][S]).
// MODE 1: bf16(gelu(acc+bias)). MODE 3: bf16 split-K partial.
template <int MODE, int NI>
__global__ __launch_bounds__(512, 2) void gemm256_kernel(
    const ushort* __restrict__ A, const ushort* __restrict__ Bt,
    const float* __restrict__ bias, const float* __restrict__ biasB,
    const float* __restrict__ biasC,
    ushort* __restrict__ outb, ushort* __restrict__ outbV,
    int M, int N, int lda, int kbeg, int klen) {
  constexpr int BN = NI * 64;
  __shared__ __align__(16) ushort As[2][256 * 64];
  __shared__ __align__(16) ushort Bs[2][BN * 64];
  int tid = threadIdx.x, lane = tid & 63, w = tid >> 6;
  int lm = lane & 15, kg = lane >> 4;
  int wr = w >> 2, wc = w & 3;
  int gx = gridDim.x, nwg = gx * gridDim.y;
  int orig = blockIdx.y * gx + blockIdx.x;
  int wg = (orig & 7) * (nwg >> 3) + (orig >> 3);
  int m0 = (wg % gx) * 256, n0 = (wg / gx) * BN;
  int kb0 = kbeg + blockIdx.z * klen;

  f32x4 acc[8][NI] = {};

  const ushort* srcA[4];
  const ushort* srcB[NI];
  int dbase[4];
#pragma unroll
  for (int q = 0; q < 4; q++) {
    int g = q * 512 + tid;
    int row = g >> 3, gc = g & 7;
    int col = (gc ^ (row & 7)) << 3;
    srcA[q] = A + (size_t)(m0 + row) * lda + kb0 + col;
    if (q < NI) srcB[q] = Bt + (size_t)(n0 + row) * lda + kb0 + col;
    dbase[q] = (q * 512 + w * 64) * 8;
  }

  const ushort* aB0 = &As[0][(wr * 128 + lm) * 64 + ((kg ^ (lm & 7)) << 3)];
  const ushort* aB1 = &As[0][(wr * 128 + lm) * 64 + (((4 + kg) ^ (lm & 7)) << 3)];
  const ushort* bB0 = &Bs[0][(wc * 16 * NI + lm) * 64 + ((kg ^ (lm & 7)) << 3)];
  const ushort* bB1 = &Bs[0][(wc * 16 * NI + lm) * 64 + (((4 + kg) ^ (lm & 7)) << 3)];

  int nK = klen >> 6;
  // prologue: tile 0 -> buf 0, order B[0..NI-1], A0, A2, A1, A3
#pragma unroll
  for (int q = 0; q < NI; q++) gl_lds16(srcB[q], &Bs[0][dbase[q]]);
  gl_lds16(srcA[0], &As[0][dbase[0]]);
  gl_lds16(srcA[2], &As[0][dbase[2]]);
  gl_lds16(srcA[1], &As[0][dbase[1]]);
  gl_lds16(srcA[3], &As[0][dbase[3]]);
  asm volatile("s_waitcnt vmcnt(2)" ::: "memory");
  __builtin_amdgcn_s_barrier();

  for (int kt = 0; kt < nK; kt++) {
    int cur = kt & 1, nxt = cur ^ 1;
    bool hn = (kt + 1 < nK);
    int ko = (kt + 1) << 6;
    const ushort* a0 = aB0 + cur * 16384;
    const ushort* a1 = aB1 + cur * 16384;
    const ushort* b0 = bB0 + cur * (BN * 64);
    const ushort* b1 = bB1 + cur * (BN * 64);

    short8 af[4][2], bfr[NI][2];

    // ---- phase A: read af(mh0) + ALL bf; stage next B; MFMA mh0 x all n ----
#pragma unroll
    for (int i = 0; i < 4; i++) {
      af[i][0] = *reinterpret_cast<const short8*>(a0 + i * 1024);
      af[i][1] = *reinterpret_cast<const short8*>(a1 + i * 1024);
    }
#pragma unroll
    for (int n = 0; n < NI; n++) {
      bfr[n][0] = *reinterpret_cast<const short8*>(b0 + n * 1024);
      bfr[n][1] = *reinterpret_cast<const short8*>(b1 + n * 1024);
    }
    if (hn) {
#pragma unroll
      for (int q = 0; q < NI; q++) gl_lds16(srcB[q] + ko, &Bs[nxt][dbase[q]]);
    }
    __builtin_amdgcn_s_barrier();
    __builtin_amdgcn_s_setprio(1);
#pragma unroll
    for (int i = 0; i < 4; i++)
#pragma unroll
      for (int n = 0; n < NI; n++)
#pragma unroll
        for (int s = 0; s < 2; s++)
          acc[i][n] = __builtin_amdgcn_mfma_f32_16x16x32_bf16(af[i][s], bfr[n][s], acc[i][n], 0, 0, 0);
    __builtin_amdgcn_s_setprio(0);
    // this tile's A1,A3 must land (per-wave) before phase B reads af(mh1);
    // outstanding after this: the NI next-tile B loads only
    if (hn) {
      if constexpr (NI == 4) asm volatile("s_waitcnt vmcnt(4)" ::: "memory");
      else if constexpr (NI == 3) asm volatile("s_waitcnt vmcnt(3)" ::: "memory");
      else asm volatile("s_waitcnt vmcnt(2)" ::: "memory");
    } else {
      asm volatile("s_waitcnt vmcnt(0)" ::: "memory");
    }
    __builtin_amdgcn_s_barrier();

    // ---- phase B: read af(mh1); stage next A; MFMA mh1 x all n ----
#pragma unroll
    for (int i = 0; i < 4; i++) {
      af[i][0] = *reinterpret_cast<const short8*>(a0 + 4096 + i * 1024);
      af[i][1] = *reinterpret_cast<const short8*>(a1 + 4096 + i * 1024);
    }
    if (hn) {
      gl_lds16(srcA[0] + ko, &As[nxt][dbase[0]]);
      gl_lds16(srcA[2] + ko, &As[nxt][dbase[2]]);
      gl_lds16(srcA[1] + ko, &As[nxt][dbase[1]]);
      gl_lds16(srcA[3] + ko, &As[nxt][dbase[3]]);
    }
    __builtin_amdgcn_s_barrier();
    __builtin_amdgcn_s_setprio(1);
#pragma unroll
    for (int i = 0; i < 4; i++)
#pragma unroll
      for (int n = 0; n < NI; n++)
#pragma unroll
        for (int s = 0; s < 2; s++)
          acc[4 + i][n] = __builtin_amdgcn_mfma_f32_16x16x32_bf16(af[i][s], bfr[n][s], acc[4 + i][n], 0, 0, 0);
    __builtin_amdgcn_s_setprio(0);
    // next tile's B + A0,A2 must land before next phase A reads
    if (hn) asm volatile("s_waitcnt vmcnt(2)" ::: "memory");
    __builtin_amdgcn_s_barrier();
  }

#pragma unroll
  for (int mi = 0; mi < 8; mi++) {
#pragma unroll
    for (int ni = 0; ni < NI; ni++) {
      int row0 = m0 + wr * 128 + mi * 16 + kg * 4;
      int col = n0 + wc * 16 * NI + ni * 16 + lm;
      f32x4 v4 = acc[mi][ni];
      if (MODE == 0) {
        if (col < 2 * H) {
          float bb = (col < H) ? bias[col] : biasB[col - H];
          float sc = (col < H) ? 0.125f : 1.0f;
          size_t base = (size_t)(col >> 11) * ((size_t)S * H) + (col & (H - 1));
#pragma unroll
          for (int r = 0; r < 4; r++)
            outb[base + (size_t)(row0 + r) * H] = f2bf((v4[r] + bb) * sc);
        } else {
          float bb = biasC[col - 2 * H];
          s16x4 pk;
#pragma unroll
          for (int r = 0; r < 4; r++) pk[r] = (short)f2bf(v4[r] + bb);
          *reinterpret_cast<s16x4*>(outbV + (size_t)(col - 2 * H) * S + row0) = pk;
        }
      } else if (MODE == 1) {
#pragma unroll
        for (int r = 0; r < 4; r++) {
          float t = v4[r] + bias[col];
          outb[(size_t)(row0 + r) * N + col] = f2bf(0.5f * t * (1.0f + erff(t * 0.70710678118f)));
        }
      } else {
#pragma unroll
        for (int r = 0; r < 4; r++)
          outb[(size_t)blockIdx.z * M * N + (size_t)(row0 + r) * N + col] = f2bf(v4[r]);
      }
    }
  }
}

// causal flash attention, folded q-pair scheduling (round-11 best).
// Block (h, x): q-blocks {x, 15-x} of 128 rows; 8 waves x 16 q-rows; KVB=128 dbuf.
__global__ __launch_bounds__(512) void attn_kernel(
    const ushort* __restrict__ Q, const ushort* __restrict__ Kmat,
    const ushort* __restrict__ VT, ushort* __restrict__ ctx) {
  __shared__ __align__(16) ushort Ks[2][128 * 64];
  __shared__ __align__(16) ushort Vs[2][64 * 128];
  __shared__ __align__(16) ushort Ps[8 * 16 * 64];
  int h = blockIdx.x;
  int x = blockIdx.y;
  int tid = threadIdx.x, lane = tid & 63, w = tid >> 6;
  int lm = lane & 15, kg = lane >> 4;

  int qbA = x, qbB = 15 - x;
  int tA = x + 1;
  const int nt = 17;

  short8 qa[2];
#pragma unroll
  for (int ks = 0; ks < 2; ks++)
    qa[ks] = *reinterpret_cast<const short8*>(
        Q + (size_t)(qbA * 128 + w * 16 + lm) * H + h * 64 + ks * 32 + kg * 8);

  float m_run[4], l_run[4];
  f32x4 o_acc[4] = {};
#pragma unroll
  for (int r = 0; r < 4; r++) { m_run[r] = -1e30f; l_run[r] = 0.f; }

  auto stage = [&](int kb, int buf) {
#pragma unroll
    for (int p = 0; p < 2; p++) {
      int gbase = p * 512 + w * 64;
      int gran = gbase + lane;
      int krow = gran >> 3, gk = gran & 7;
      gl_lds16(Kmat + (size_t)(kb * 128 + krow) * H + h * 64 + ((gk ^ (krow & 7)) << 3),
               &Ks[buf][gbase * 8]);
    }
#pragma unroll
    for (int p = 0; p < 2; p++) {
      int gbase = p * 512 + w * 64;
      int gran = gbase + lane;
      int vrow = gran >> 4, gv = gran & 15;
      gl_lds16(VT + (size_t)(h * 64 + vrow) * S + kb * 128 + ((gv ^ (vrow & 15)) << 3),
               &Vs[buf][gbase * 8]);
    }
  };

  stage(0, 0);
  __syncthreads();

  for (int t = 0; t < nt; t++) {
    int cur = t & 1;
    if (t + 1 < nt) {
      int tn = t + 1;
      stage((tn < tA) ? tn : tn - tA, cur ^ 1);
    }
    bool diag = (t == tA - 1) || (t == nt - 1);

    f32x4 sacc[8] = {};
#pragma unroll
    for (int j = 0; j < 8; j++) {
      int krow = j * 16 + lm;
#pragma unroll
      for (int ks = 0; ks < 2; ks++) {
        short8 kf = *reinterpret_cast<const short8*>(
            &Ks[cur][krow * 64 + (((ks * 4 + kg) ^ (lm & 7)) << 3)]);
        sacc[j] = __builtin_amdgcn_mfma_f32_16x16x32_bf16(qa[ks], kf, sacc[j], 0, 0, 0);
      }
    }
    if (diag) {
#pragma unroll
      for (int j = 0; j < 8; j++)
#pragma unroll
        for (int r = 0; r < 4; r++)
          if (j * 16 + lm > w * 16 + kg * 4 + r) sacc[j][r] = -1e30f;
    }

#pragma unroll
    for (int r = 0; r < 4; r++) {
      float mx = sacc[0][r];
#pragma unroll
      for (int j = 1; j < 8; j++) mx = fmaxf(mx, sacc[j][r]);
      mx = fmaxf(mx, __shfl_xor(mx, 1, 64));
      mx = fmaxf(mx, __shfl_xor(mx, 2, 64));
      mx = fmaxf(mx, __shfl_xor(mx, 4, 64));
      mx = fmaxf(mx, __shfl_xor(mx, 8, 64));
      float mnew = fmaxf(m_run[r], mx);
      float sc = __expf(m_run[r] - mnew);
      m_run[r] = mnew;
      float ps = 0.f;
#pragma unroll
      for (int j = 0; j < 8; j++) {
        float p = __expf(sacc[j][r] - mnew);
        sacc[j][r] = p;
        ps += p;
      }
      ps += __shfl_xor(ps, 1, 64);
      ps += __shfl_xor(ps, 2, 64);
      ps += __shfl_xor(ps, 4, 64);
      ps += __shfl_xor(ps, 8, 64);
      l_run[r] = l_run[r] * sc + ps;
#pragma unroll
      for (int jd = 0; jd < 4; jd++) o_acc[jd][r] *= sc;
    }

#pragma unroll
    for (int c = 0; c < 2; c++) {
#pragma unroll
      for (int jj = 0; jj < 4; jj++)
#pragma unroll
        for (int r = 0; r < 4; r++) {
          int rl = kg * 4 + r;
          int col = jj * 16 + lm;
          Ps[w * 1024 + rl * 64 + (((col >> 3) ^ (rl & 7)) << 3) + (col & 7)] =
              f2bf(sacc[c * 4 + jj][r]);
        }
      short8 pa[2];
#pragma unroll
      for (int ks = 0; ks < 2; ks++)
        pa[ks] = *reinterpret_cast<const short8*>(
            &Ps[w * 1024 + lm * 64 + (((ks * 4 + kg) ^ (lm & 7)) << 3)]);
#pragma unroll
      for (int jd = 0; jd < 4; jd++) {
        int d = jd * 16 + lm;
#pragma unroll
        for (int ks = 0; ks < 2; ks++) {
          short8 vf = *reinterpret_cast<const short8*>(
              &Vs[cur][d * 128 + (((c * 8 + ks * 4 + kg) ^ lm) << 3)]);
          o_acc[jd] = __builtin_amdgcn_mfma_f32_16x16x32_bf16(pa[ks], vf, o_acc[jd], 0, 0, 0);
        }
      }
    }

    if (t == tA - 1) {
#pragma unroll
      for (int jd = 0; jd < 4; jd++)
#pragma unroll
        for (int r = 0; r < 4; r++)
          ctx[(size_t)(qbA * 128 + w * 16 + kg * 4 + r) * H + h * 64 + jd * 16 + lm] =
              f2bf(o_acc[jd][r] / l_run[r]);
#pragma unroll
      for (int r = 0; r < 4; r++) { m_run[r] = -1e30f; l_run[r] = 0.f; }
#pragma unroll
      for (int jd = 0; jd < 4; jd++) o_acc[jd] = f32x4{0.f, 0.f, 0.f, 0.f};
#pragma unroll
      for (int ks = 0; ks < 2; ks++)
        qa[ks] = *reinterpret_cast<const short8*>(
            Q + (size_t)(qbB * 128 + w * 16 + lm) * H + h * 64 + ks * 32 + kg * 8);
    }
    __syncthreads();
  }

#pragma unroll
  for (int jd = 0; jd < 4; jd++)
#pragma unroll
    for (int r = 0; r < 4; r++)
      ctx[(size_t)(qbB * 128 + w * 16 + kg * 4 + r) * H + h * 64 + jd * 16 + lm] =
          f2bf(o_acc[jd][r] / l_run[r]);
}

extern "C" void kernel_launch(void* const* d_in, const int* in_sizes, int n_in,
                              void* d_out, int out_size, void* d_ws, size_t ws_size,
                              hipStream_t stream) {
  const float* x = (const float*)d_in[0];
  const float* ln1w = (const float*)d_in[2];
  const float* ln1b = (const float*)d_in[3];
  const float* wq = (const float*)d_in[4];
  const float* bq = (const float*)d_in[5];
  const float* wk = (const float*)d_in[6];
  const float* bk = (const float*)d_in[7];
  const float* wv = (const float*)d_in[8];
  const float* bv = (const float*)d_in[9];
  const float* wo = (const float*)d_in[10];
  const float* bo = (const float*)d_in[11];
  const float* w1 = (const float*)d_in[12];
  const float* b1 = (const float*)d_in[13];
  const float* w2 = (const float*)d_in[14];
  const float* b2 = (const float*)d_in[15];
  const float* ln2w = (const float*)d_in[16];
  const float* ln2b = (const float*)d_in[17];
  float* out = (float*)d_out;

  char* ws = (char*)d_ws;
  const size_t MB = 1024 * 1024;
  const size_t SH = (size_t)S * H;
  ushort* WT_QKV = (ushort*)(ws);               // 0-24MB, dead after QKV gemm
  ushort* WT_O = (ushort*)(ws + 24 * MB);       // 24-32
  ushort* WT_1 = (ushort*)(ws + 32 * MB);       // 32-64, dead after MLP1
  ushort* WT_2 = (ushort*)(ws + 64 * MB);       // 64-96
  ushort* LNO = (ushort*)(ws + 96 * MB);        // 96-104
  ushort* QKVB = (ushort*)(ws + 104 * MB);      // Q,K: 104-120, dead after attn
  ushort* VTb = (ushort*)(ws + 128 * MB);       // V transposed [H][S]: 128-136
  ushort* CTX = (ushort*)(ws + 136 * MB);       // 136-144
  float* X1 = (float*)(ws + 144 * MB);          // 144-160
  ushort* MID = (ushort*)(ws);                  // 0-32 (over dead WT_QKV+WT_O)
  ushort* SPA = (ushort*)(ws + 104 * MB);       // attn-out bf16 partials {0,1}: 104-120
  ushort* SPM = (ushort*)(ws + 32 * MB);        // MLP2 bf16 partials {0,1}: 32-48 (over dead WT_1)

  transpose_all_kernel<<<12288, 256, 0, stream>>>(
      wq, wk, wv, wo, w1, w2, WT_QKV, WT_O, WT_1, WT_2);

  ln_kernel<<<S, 256, 0, stream>>>(x, ln1w, ln1b, LNO);

  // QKV: BN=192 -> 256 blocks; V written transposed directly into VTb
  gemm256_kernel<0, 3><<<dim3(S / 256, 3 * H / 192), 512, 0, stream>>>(
      LNO, WT_QKV, bq, bk, bv, QKVB, VTb, S, 3 * H, H, 0, H);

  attn_kernel<<<dim3(NH, 8), 512, 0, stream>>>(QKVB, QKVB + SH, VTb, CTX);

  // attn-out: BN=128, split-K2 -> 256 blocks, bf16 partials
  gemm256_kernel<3, 2><<<dim3(S / 256, H / 128, 2), 512, 0, stream>>>(
      CTX, WT_O, nullptr, nullptr, nullptr, SPA, nullptr, S, H, H, 0, H / 2);
  combine_ln_kernel<<<S, 256, 0, stream>>>(x, SPA, SPA + SH, bo, ln2w, ln2b, X1, LNO);

  gemm256_kernel<1, 4><<<dim3(S / 256, DFF / 256), 512, 0, stream>>>(
      LNO, WT_1, b1, nullptr, nullptr, MID, nullptr, S, DFF, H, 0, H);

  // MLP2: BN=128, split-K2 -> 256 blocks, bf16 partials
  gemm256_kernel<3, 2><<<dim3(S / 256, H / 128, 2), 512, 0, stream>>>(
      MID, WT_2, nullptr, nullptr, nullptr, SPM, nullptr, S, H, DFF, 0, DFF / 2);
  combine2_kernel<<<SH / 2048, 256, 0, stream>>>(X1, SPM, SPM + SH, b2, out);
}